// Round 10
// baseline (167.934 us; speedup 1.0000x reference)
//
#include <hip/hip_runtime.h>

// GConvGRU with H=0: only two ChebConvs on X survive.
//   Z  = sigmoid(X@Wz0 + Tx1@Wz1 + Tx2@Wz2 + b_xz + b_hz)
//   Ht = tanh   (X@Wh0 + Tx1@Wh1 + Tx2@Wh2 + b_xh + b_hh)
//   H_new = (1-Z)*Ht
// R10: producers emit bf16 hi/lo planes (split-precision), k_gru is pure
// MFMA (no LDS/syncs/converts). cv stores raw w; dinv applied at spmm
// writeback (row-local). Xs = dinv*X precomputed in k_degx (block-local dinv).
//   t1[d] = -dinv[d]*sum w*Xs[s];  u1[d] = dinv[d]*t1[d]
//   t2[d] = -2*dinv[d]*sum w*u1[s] - X[d]

#define N_NODES 50000
#define E_EDGES 800000
#define NC 64
#define BSH 6
#define BUKN 64
#define NBUK 782              // ceil(50000/64); NBUK*64 = 50048
#define NPADROW 50048
#define EPB 2048
#define NBLK 391
#define CSR_CAP 1536          // LDS record staging cap per bucket

// ws element offsets (4B units). No aliasing - 86MB of the 256MB ws.
#define OFF_CV       0          // ll[800000]
#define OFF_ROWSTART 1600000    // int[50016]
#define OFF_TOTD     1650016
#define OFF_BASED    1650800
#define OFF_TOTS     1651584
#define OFF_BASES    1652368    // ends 1653152
#define OFF_XS       1653152    // float[3200000] = dinv*X (spmm1 gather src)
#define OFF_U1       4853152    // float[3200000] = dinv^2*t1raw (spmm2 gather src)
#define OFF_RECD     8053152    // ll[800000]
#define OFF_RECS     9653152    // ll[800000]
#define OFF_DINV     11253152   // float[50048]
#define OFF_CNTD     11303200   // int[305762]
#define OFF_CNTS     11608962   // int[305762]
#define OFF_WB       11914724   // short[49152] bf16 weight planes
#define OFF_XHI      11939300   // short[50048*64] each plane below
#define OFF_XLO      13540836
#define OFF_T1HI     15142372
#define OFF_T1LO     16743908
#define OFF_T2HI     18345444
#define OFF_T2LO     19946980   // ends 21548516

typedef __attribute__((ext_vector_type(8))) short bf16x8;
typedef __attribute__((ext_vector_type(4))) float f32x4;

__device__ __forceinline__ unsigned bf16rne(float x) {
    unsigned u = __float_as_uint(x);
    return (u + 0x7fffu + ((u >> 16) & 1u)) >> 16;
}

// hist blocks bin edges; 6 extra blocks build bf16 weight planes.
__global__ __launch_bounds__(256) void k_hist(const int* __restrict__ ei,
        int* __restrict__ cntD, int* __restrict__ cntS,
        const float* __restrict__ Wz, const float* __restrict__ Wh,
        short* __restrict__ WB) {
    int t = threadIdx.x, blk = blockIdx.x;
    if (blk >= NBLK) {
        int mg = blk - NBLK;            // 0..5 = (m,g)
        int m = mg >> 1, g = mg & 1;
        const float* W = (g ? Wh : Wz) + m * 4096;
        #pragma unroll
        for (int r = 0; r < 16; ++r) {
            int idx = r * 256 + t;      // c*64 + o
            int c = idx >> 6, o = idx & 63;
            float x = W[idx];
            unsigned hi = bf16rne(x);
            float fhi = __uint_as_float(hi << 16);
            unsigned lo = bf16rne(x - fhi);
            WB[(mg * 2 + 0) * 4096 + o * 64 + c] = (short)hi;
            WB[(mg * 2 + 1) * 4096 + o * 64 + c] = (short)lo;
        }
        return;
    }
    __shared__ int hD[NBUK], hS[NBUK];
    for (int b = t; b < NBUK; b += 256) { hD[b] = 0; hS[b] = 0; }
    __syncthreads();
    int e0 = blk * EPB;
    #pragma unroll
    for (int i = 0; i < 8; ++i) {
        int e = e0 + i * 256 + t;
        if (e < E_EDGES) {
            atomicAdd(&hS[ei[e] >> BSH], 1);
            atomicAdd(&hD[ei[E_EDGES + e] >> BSH], 1);
        }
    }
    __syncthreads();
    for (int b = t; b < NBUK; b += 256) {
        cntD[b * NBLK + blk] = hD[b];
        cntS[b * NBLK + blk] = hS[b];
    }
}

__global__ __launch_bounds__(256) void k_scanPB(int* __restrict__ cntD,
        int* __restrict__ cntS, int* __restrict__ totD, int* __restrict__ totS) {
    __shared__ int s[512];
    int t = threadIdx.x;
    int row = blockIdx.x; int* cnt; int* tot;
    if (row < NBUK) { cnt = cntD; tot = totD; }
    else            { row -= NBUK; cnt = cntS; tot = totS; }
    int v0 = (t < NBLK) ? cnt[row * NBLK + t] : 0;
    int v1 = (256 + t < NBLK) ? cnt[row * NBLK + 256 + t] : 0;
    s[t] = v0; s[256 + t] = v1;
    __syncthreads();
    for (int off = 1; off < 512; off <<= 1) {
        int a = (t >= off) ? s[t - off] : 0;
        int b = (256 + t >= off) ? s[256 + t - off] : 0;
        __syncthreads();
        s[t] += a; s[256 + t] += b;
        __syncthreads();
    }
    if (t < NBLK) cnt[row * NBLK + t] = s[t] - v0;
    if (256 + t < NBLK) cnt[row * NBLK + 256 + t] = s[256 + t] - v1;
    if (t == 0) tot[row] = s[511];
}

__global__ __launch_bounds__(256) void k_scanTot(int* __restrict__ totD,
        int* __restrict__ baseD, int* __restrict__ totS, int* __restrict__ baseS) {
    __shared__ int s[1024];
    int t = threadIdx.x;
    int* tot  = blockIdx.x ? totS  : totD;
    int* base = blockIdx.x ? baseS : baseD;
    int v[4];
    #pragma unroll
    for (int q = 0; q < 4; ++q) {
        int i = q * 256 + t;
        v[q] = (i < NBUK) ? tot[i] : 0;
        s[i] = v[q];
    }
    __syncthreads();
    for (int off = 1; off < 1024; off <<= 1) {
        int a[4];
        #pragma unroll
        for (int q = 0; q < 4; ++q) {
            int i = q * 256 + t;
            a[q] = (i >= off) ? s[i - off] : 0;
        }
        __syncthreads();
        #pragma unroll
        for (int q = 0; q < 4; ++q) s[q * 256 + t] += a[q];
        __syncthreads();
    }
    #pragma unroll
    for (int q = 0; q < 4; ++q) {
        int i = q * 256 + t;
        if (i < NBUK) base[i] = s[i] - v[q];
    }
}

__global__ __launch_bounds__(256) void k_scatter(const int* __restrict__ ei,
        const float* __restrict__ ew, const int* __restrict__ offD,
        const int* __restrict__ offS, const int* __restrict__ baseD,
        const int* __restrict__ baseS, long long* __restrict__ recD,
        long long* __restrict__ recS) {
    __shared__ int curD[NBUK], curS[NBUK];
    int t = threadIdx.x, blk = blockIdx.x;
    for (int b = t; b < NBUK; b += 256) {
        curD[b] = baseD[b] + offD[b * NBLK + blk];
        curS[b] = baseS[b] + offS[b * NBLK + blk];
    }
    __syncthreads();
    int e0 = blk * EPB;
    #pragma unroll
    for (int i = 0; i < 8; ++i) {
        int e = e0 + i * 256 + t;
        if (e < E_EDGES) {
            int sN = ei[e], dN = ei[E_EDGES + e];
            long long wb = (long long)(unsigned)__float_as_uint(ew[e]) << 32;
            int pD = atomicAdd(&curD[dN >> BSH], 1);
            recD[pD] = wb | (unsigned)((sN << BSH) | (dN & (BUKN - 1)));
            int pS = atomicAdd(&curS[sN >> BSH], 1);
            recS[pS] = wb | (unsigned)(sN & (BUKN - 1));
        }
    }
}

// deg -> dinv, then block-local X conversion: Xs = dinv*X, X bf16 hi/lo planes.
__global__ __launch_bounds__(256) void k_degx(const long long* __restrict__ recS,
        const int* __restrict__ totS, const int* __restrict__ baseS,
        const float* __restrict__ X, float* __restrict__ dinv,
        float* __restrict__ xs, short* __restrict__ xhi, short* __restrict__ xlo) {
    __shared__ float degL[BUKN], dinvL[BUKN];
    int t = threadIdx.x, b = blockIdx.x;
    if (t < BUKN) degL[t] = 0.f;
    __syncthreads();
    int st = baseS[b], n = totS[b];
    for (int i = t; i < n; i += 256) {
        long long r = recS[st + i];
        atomicAdd(&degL[(int)(r & (BUKN - 1))], __uint_as_float((unsigned)(r >> 32)));
    }
    __syncthreads();
    if (t < BUKN) {
        int node = b * BUKN + t;
        float dg = degL[t];
        float dv = (node < N_NODES && dg > 0.f) ? rsqrtf(dg) : 0.f;
        dinvL[t] = dv;
        if (node < N_NODES) dinv[node] = dv;
    }
    __syncthreads();
    #pragma unroll
    for (int it = 0; it < 4; ++it) {
        int fidx = it * 256 + t;          // 0..1023 float4 units
        int rl = fidx >> 4, c4 = fidx & 15;
        int gn = b * BUKN + rl;
        float4 v = make_float4(0.f, 0.f, 0.f, 0.f);
        if (gn < N_NODES) v = *(const float4*)&X[(size_t)gn * 64 + c4 * 4];
        float dv = dinvL[rl];
        if (gn < N_NODES) {
            float4 sv = make_float4(dv * v.x, dv * v.y, dv * v.z, dv * v.w);
            *(float4*)&xs[(size_t)gn * 64 + c4 * 4] = sv;
        }
        unsigned h0 = bf16rne(v.x), h1 = bf16rne(v.y),
                 h2 = bf16rne(v.z), h3 = bf16rne(v.w);
        unsigned q0 = bf16rne(v.x - __uint_as_float(h0 << 16));
        unsigned q1 = bf16rne(v.y - __uint_as_float(h1 << 16));
        unsigned q2 = bf16rne(v.z - __uint_as_float(h2 << 16));
        unsigned q3 = bf16rne(v.w - __uint_as_float(h3 << 16));
        *(uint2*)&xhi[(size_t)gn * 64 + c4 * 4] = make_uint2(h0 | (h1 << 16), h2 | (h3 << 16));
        *(uint2*)&xlo[(size_t)gn * 64 + c4 * 4] = make_uint2(q0 | (q1 << 16), q2 | (q3 << 16));
    }
}

// Bucket records -> exact CSR (val = raw w), LDS-staged single global read.
__global__ __launch_bounds__(256) void k_csr(const long long* __restrict__ recD,
        const int* __restrict__ totD, const int* __restrict__ baseD,
        long long* __restrict__ cv, int* __restrict__ row_start) {
    __shared__ long long recL[CSR_CAP];
    __shared__ int cnt[BUKN], cur[BUKN];
    int t = threadIdx.x, b = blockIdx.x;
    if (t < BUKN) cnt[t] = 0;
    __syncthreads();
    int st = baseD[b], n = totD[b];
    bool fits = (n <= CSR_CAP);
    for (int i = t; i < n; i += 256) {
        long long r = recD[st + i];
        if (fits) recL[i] = r;
        atomicAdd(&cnt[(int)(r & (BUKN - 1))], 1);
    }
    __syncthreads();
    if (t < BUKN) {
        int x = cnt[t];
        int orig = x;
        #pragma unroll
        for (int off = 1; off < BUKN; off <<= 1) {
            int v = __shfl_up(x, off, 64);
            if ((t & 63) >= off) x += v;
        }
        cur[t] = x - orig;
        int node = b * BUKN + t;
        if (node < N_NODES) row_start[node] = st + (x - orig);
    }
    if (b == 0 && t == 0) row_start[N_NODES] = E_EDGES;
    __syncthreads();
    for (int i = t; i < n; i += 256) {
        long long r = fits ? recL[i] : recD[st + i];
        int m = (int)(r & 0xffffffffLL);
        int rr = m & (BUKN - 1);
        int sN = m >> BSH;
        int pos = st + atomicAdd(&cur[rr], 1);
        cv[pos] = (r & 0xffffffff00000000LL) | (unsigned)sN;   // (w, src)
    }
}

// SpMM: wave per row; 16 lanes/edge x 4 edges/instr float4 gathers.
// PASS 1: gather xs;  t1 = -dv*acc; write u1 = dv*t1 (f32) + t1 bf16 planes.
// PASS 2: gather u1;  t2 = -2*dv*acc - X[d]; write t2 bf16 planes.
template<int PASS>
__global__ __launch_bounds__(256) void k_spmm(
        const int* __restrict__ row_start, const long long* __restrict__ cv,
        const float* __restrict__ gsrc, const float* __restrict__ X,
        const float* __restrict__ dinv, float* __restrict__ u1,
        short* __restrict__ phi, short* __restrict__ plo) {
    int wid = (blockIdx.x << 2) + (threadIdx.x >> 6);
    int l = threadIdx.x & 63;
    if (wid >= N_NODES) return;
    int start = row_start[wid];
    int end   = row_start[wid + 1];
    int sub = l >> 4;
    int q   = l & 15;
    float4 acc = make_float4(0.f, 0.f, 0.f, 0.f);
    #pragma unroll 2
    for (int j = start; j < end; j += 8) {
        int jA = j + sub;
        int jB = j + 4 + sub;
        long long pA = (jA < end) ? cv[jA] : 0LL;
        long long pB = (jB < end) ? cv[jB] : 0LL;
        float4 xA = *(const float4*)&gsrc[(size_t)(unsigned)(pA & 0xffffffffLL) * NC + q * 4];
        float4 xB = *(const float4*)&gsrc[(size_t)(unsigned)(pB & 0xffffffffLL) * NC + q * 4];
        float vA = __int_as_float((int)(pA >> 32));
        float vB = __int_as_float((int)(pB >> 32));
        acc.x = fmaf(vA, xA.x, acc.x); acc.y = fmaf(vA, xA.y, acc.y);
        acc.z = fmaf(vA, xA.z, acc.z); acc.w = fmaf(vA, xA.w, acc.w);
        acc.x = fmaf(vB, xB.x, acc.x); acc.y = fmaf(vB, xB.y, acc.y);
        acc.z = fmaf(vB, xB.z, acc.z); acc.w = fmaf(vB, xB.w, acc.w);
    }
    #pragma unroll
    for (int m = 16; m <= 32; m <<= 1) {
        acc.x += __shfl_xor(acc.x, m, 64);
        acc.y += __shfl_xor(acc.y, m, 64);
        acc.z += __shfl_xor(acc.z, m, 64);
        acc.w += __shfl_xor(acc.w, m, 64);
    }
    if (sub == 0) {
        float dv = dinv[wid];
        float4 r;
        if (PASS == 1) {
            r.x = -dv * acc.x; r.y = -dv * acc.y;
            r.z = -dv * acc.z; r.w = -dv * acc.w;
            *(float4*)&u1[(size_t)wid * NC + q * 4] =
                make_float4(dv * r.x, dv * r.y, dv * r.z, dv * r.w);
        } else {
            const float4 xo = *(const float4*)&X[(size_t)wid * NC + q * 4];
            r.x = -2.f * dv * acc.x - xo.x; r.y = -2.f * dv * acc.y - xo.y;
            r.z = -2.f * dv * acc.z - xo.z; r.w = -2.f * dv * acc.w - xo.w;
        }
        unsigned h0 = bf16rne(r.x), h1 = bf16rne(r.y),
                 h2 = bf16rne(r.z), h3 = bf16rne(r.w);
        unsigned q0 = bf16rne(r.x - __uint_as_float(h0 << 16));
        unsigned q1 = bf16rne(r.y - __uint_as_float(h1 << 16));
        unsigned q2 = bf16rne(r.z - __uint_as_float(h2 << 16));
        unsigned q3 = bf16rne(r.w - __uint_as_float(h3 << 16));
        *(uint2*)&phi[(size_t)wid * NC + q * 4] = make_uint2(h0 | (h1 << 16), h2 | (h3 << 16));
        *(uint2*)&plo[(size_t)wid * NC + q * 4] = make_uint2(q0 | (q1 << 16), q2 | (q3 << 16));
    }
}

// Pure-MFMA GRU: no LDS, no syncs. A-frags direct from bf16 planes (L2-hot),
// B-frags from WB. 4 waves = 4 o-tiles; 144 MFMA/wave.
__global__ __launch_bounds__(256) void k_gru(
        const short* __restrict__ xhi, const short* __restrict__ xlo,
        const short* __restrict__ t1hi, const short* __restrict__ t1lo,
        const short* __restrict__ t2hi, const short* __restrict__ t2lo,
        const short* __restrict__ WB,
        const float* __restrict__ bxz, const float* __restrict__ bhz,
        const float* __restrict__ bxh, const float* __restrict__ bhh,
        float* __restrict__ out) {
    int tid = threadIdx.x;
    int l = tid & 63;
    int w = tid >> 6;
    int node0 = blockIdx.x * 64;

    f32x4 accz[4], acch[4];
    #pragma unroll
    for (int mt = 0; mt < 4; ++mt) {
        accz[mt] = (f32x4){0.f, 0.f, 0.f, 0.f};
        acch[mt] = (f32x4){0.f, 0.f, 0.f, 0.f};
    }

    const short* PHI[3] = {xhi, t1hi, t2hi};
    const short* PLO[3] = {xlo, t1lo, t2lo};
    int o = w * 16 + (l & 15);

    #pragma unroll
    for (int m = 0; m < 3; ++m) {
        const short* phi = PHI[m];
        const short* plo = PLO[m];
        const short* wbm = WB + m * 4 * 4096;
        #pragma unroll
        for (int kt = 0; kt < 2; ++kt) {
            int k0 = kt * 32 + (l >> 4) * 8;
            bf16x8 ah[4], al[4];
            #pragma unroll
            for (int mt = 0; mt < 4; ++mt) {
                size_t rowoff = (size_t)(node0 + mt * 16 + (l & 15)) * 64 + k0;
                ah[mt] = *(const bf16x8*)&phi[rowoff];
                al[mt] = *(const bf16x8*)&plo[rowoff];
            }
            bf16x8 bzh = *(const bf16x8*)&wbm[0 * 4096 + o * 64 + k0];
            bf16x8 bzl = *(const bf16x8*)&wbm[1 * 4096 + o * 64 + k0];
            bf16x8 bhh_ = *(const bf16x8*)&wbm[2 * 4096 + o * 64 + k0];
            bf16x8 bhl = *(const bf16x8*)&wbm[3 * 4096 + o * 64 + k0];
            #pragma unroll
            for (int mt = 0; mt < 4; ++mt) {
                accz[mt] = __builtin_amdgcn_mfma_f32_16x16x32_bf16(ah[mt], bzh, accz[mt], 0, 0, 0);
                accz[mt] = __builtin_amdgcn_mfma_f32_16x16x32_bf16(ah[mt], bzl, accz[mt], 0, 0, 0);
                accz[mt] = __builtin_amdgcn_mfma_f32_16x16x32_bf16(al[mt], bzh, accz[mt], 0, 0, 0);
                acch[mt] = __builtin_amdgcn_mfma_f32_16x16x32_bf16(ah[mt], bhh_, acch[mt], 0, 0, 0);
                acch[mt] = __builtin_amdgcn_mfma_f32_16x16x32_bf16(ah[mt], bhl, acch[mt], 0, 0, 0);
                acch[mt] = __builtin_amdgcn_mfma_f32_16x16x32_bf16(al[mt], bhh_, acch[mt], 0, 0, 0);
            }
        }
    }

    float bz = bxz[o] + bhz[o];
    float bh = bxh[o] + bhh[o];
    #pragma unroll
    for (int mt = 0; mt < 4; ++mt) {
        #pragma unroll
        for (int r = 0; r < 4; ++r) {
            int node = node0 + mt * 16 + (l >> 4) * 4 + r;
            if (node < N_NODES) {
                float z = accz[mt][r] + bz;
                float h = acch[mt][r] + bh;
                float sig = 1.f / (1.f + __expf(-z));
                float e2 = __expf(-2.f * h);
                float th = (1.f - e2) / (1.f + e2);
                out[(size_t)node * 64 + o] = (1.f - sig) * th;
            }
        }
    }
}

extern "C" void kernel_launch(void* const* d_in, const int* in_sizes, int n_in,
                              void* d_out, int out_size, void* d_ws, size_t ws_size,
                              hipStream_t stream) {
    const float* X   = (const float*)d_in[0];
    const int*   ei  = (const int*)d_in[1];
    const float* ew  = (const float*)d_in[2];
    const float* Wxz = (const float*)d_in[3];
    const float* Wxh = (const float*)d_in[7];
    const float* bxz = (const float*)d_in[9];
    const float* bhz = (const float*)d_in[10];
    const float* bxh = (const float*)d_in[13];
    const float* bhh = (const float*)d_in[14];
    float* out = (float*)d_out;

    int* ws_i = (int*)d_ws;
    float* ws_f = (float*)d_ws;

    long long* cv       = (long long*)(ws_i + OFF_CV);
    int*       rowstart = ws_i + OFF_ROWSTART;
    int*       totD     = ws_i + OFF_TOTD;
    int*       baseD    = ws_i + OFF_BASED;
    int*       totS     = ws_i + OFF_TOTS;
    int*       baseS    = ws_i + OFF_BASES;
    float*     xs       = ws_f + OFF_XS;
    float*     u1       = ws_f + OFF_U1;
    long long* recD     = (long long*)(ws_i + OFF_RECD);
    long long* recS     = (long long*)(ws_i + OFF_RECS);
    float*     dinv     = ws_f + OFF_DINV;
    int*       cntD     = ws_i + OFF_CNTD;
    int*       cntS     = ws_i + OFF_CNTS;
    short*     WB       = (short*)(ws_i + OFF_WB);
    short*     xhi      = (short*)(ws_i + OFF_XHI);
    short*     xlo      = (short*)(ws_i + OFF_XLO);
    short*     t1hi     = (short*)(ws_i + OFF_T1HI);
    short*     t1lo     = (short*)(ws_i + OFF_T1LO);
    short*     t2hi     = (short*)(ws_i + OFF_T2HI);
    short*     t2lo     = (short*)(ws_i + OFF_T2LO);

    const int TB = 256;
    k_hist<<<NBLK + 6, TB, 0, stream>>>(ei, cntD, cntS, Wxz, Wxh, WB);
    k_scanPB<<<2 * NBUK, TB, 0, stream>>>(cntD, cntS, totD, totS);
    k_scanTot<<<2, TB, 0, stream>>>(totD, baseD, totS, baseS);
    k_scatter<<<NBLK, TB, 0, stream>>>(ei, ew, cntD, cntS, baseD, baseS, recD, recS);
    k_degx<<<NBUK, TB, 0, stream>>>(recS, totS, baseS, X, dinv, xs, xhi, xlo);
    k_csr<<<NBUK, TB, 0, stream>>>(recD, totD, baseD, cv, rowstart);

    k_spmm<1><<<(N_NODES + 3) / 4, TB, 0, stream>>>(rowstart, cv, xs, X, dinv, u1, t1hi, t1lo);
    k_spmm<2><<<(N_NODES + 3) / 4, TB, 0, stream>>>(rowstart, cv, u1, X, dinv, u1, t2hi, t2lo);

    k_gru<<<NBUK, TB, 0, stream>>>(xhi, xlo, t1hi, t1lo, t2hi, t2lo, WB,
                                   bxz, bhz, bxh, bhh, out);
}

// Round 11
// 151.356 us; speedup vs baseline: 1.1095x; 1.1095x over previous
//
#include <hip/hip_runtime.h>

// GConvGRU with H=0: only two ChebConvs on X survive.
//   Z  = sigmoid(X@Wz0 + Tx1@Wz1 + Tx2@Wz2 + b_xz + b_hz)
//   Ht = tanh   (X@Wh0 + Tx1@Wh1 + Tx2@Wh2 + b_xh + b_hh)
//   H_new = (1-Z)*Ht
// R11 = R9 (proven 147us) + k_gru re-tiled: 32-node tiles (1563 blocks,
// 2x wave parallelism vs 782) + single-phase LDS staging of all 3 matrices
// (1 barrier, 6 independent global loads/thread). R10 post-mortem: gru is
// latency-bound by blocks/CU, not by conversion VALU.

#define N_NODES 50000
#define E_EDGES 800000
#define NC 64
#define BSH 6                 // 64 nodes per bucket
#define BUKN 64
#define NBUK 782              // ceil(50000/64)
#define EPB 2048              // edges per hist/scatter block
#define NBLK 391              // ceil(800000/2048)
#define GRUB 1563             // ceil(50000/32) gru blocks (32-node tiles)

// ws element offsets (4B units); aliases are dead before their host buffer is written
#define OFF_CV       0          // long long[800000] (exact CSR: val|src)
#define OFF_ROWSTART 1600000    // int[50001] (pad 50016)
#define OFF_TOTD     1650016    // int[784]
#define OFF_BASED    1650800    // int[784]
#define OFF_TOTS     1651584    // int[784]
#define OFF_BASES    1652368    // int[784]
#define OFF_TX1      1653152    // float[3200000]
#define OFF_RECD     1653152    //   alias: long long[800000], dead after k_csr
#define OFF_DINV     3253152    //   alias: float[50016], dead after k_csr
#define OFF_CNTD     3303168    //   alias: int[782*391], dead after k_scatter
#define OFF_TX2      4853152    // float[3200000] (ends 8053152)
#define OFF_RECS     4853152    //   alias: long long[800000], dead after k_deg
#define OFF_CNTS     6453152    //   alias: int[782*391], dead after k_scatter
#define OFF_WB       8053152    // short[49152] bf16 weight planes (past TX2)

typedef __attribute__((ext_vector_type(8))) short bf16x8;
typedef __attribute__((ext_vector_type(4))) float f32x4;

__device__ __forceinline__ unsigned bf16rne(float x) {
    unsigned u = __float_as_uint(x);
    return (u + 0x7fffu + ((u >> 16) & 1u)) >> 16;
}

// hist blocks bin edges; extra 6 blocks build bf16 weight planes (prepw).
__global__ __launch_bounds__(256) void k_hist(const int* __restrict__ ei,
        int* __restrict__ cntD, int* __restrict__ cntS,
        const float* __restrict__ Wz, const float* __restrict__ Wh,
        short* __restrict__ WB) {
    int t = threadIdx.x, blk = blockIdx.x;
    if (blk >= NBLK) {                  // prepw part
        int mg = blk - NBLK;            // 0..5 = (m,g)
        int m = mg >> 1, g = mg & 1;
        const float* W = (g ? Wh : Wz) + m * 4096;
        #pragma unroll
        for (int r = 0; r < 16; ++r) {
            int idx = r * 256 + t;      // c*64 + o
            int c = idx >> 6, o = idx & 63;
            float x = W[idx];
            unsigned hi = bf16rne(x);
            float fhi = __uint_as_float(hi << 16);
            unsigned lo = bf16rne(x - fhi);
            WB[(mg * 2 + 0) * 4096 + o * 64 + c] = (short)hi;
            WB[(mg * 2 + 1) * 4096 + o * 64 + c] = (short)lo;
        }
        return;
    }
    __shared__ int hD[NBUK], hS[NBUK];
    for (int b = t; b < NBUK; b += 256) { hD[b] = 0; hS[b] = 0; }
    __syncthreads();
    int e0 = blk * EPB;
    #pragma unroll
    for (int i = 0; i < 8; ++i) {
        int e = e0 + i * 256 + t;
        if (e < E_EDGES) {
            atomicAdd(&hS[ei[e] >> BSH], 1);
            atomicAdd(&hD[ei[E_EDGES + e] >> BSH], 1);
        }
    }
    __syncthreads();
    for (int b = t; b < NBUK; b += 256) {
        cntD[b * NBLK + blk] = hD[b];
        cntS[b * NBLK + blk] = hS[b];
    }
}

__global__ __launch_bounds__(256) void k_scanPB(int* __restrict__ cntD,
        int* __restrict__ cntS, int* __restrict__ totD, int* __restrict__ totS) {
    __shared__ int s[512];
    int t = threadIdx.x;
    int row = blockIdx.x; int* cnt; int* tot;
    if (row < NBUK) { cnt = cntD; tot = totD; }
    else            { row -= NBUK; cnt = cntS; tot = totS; }
    int v0 = (t < NBLK) ? cnt[row * NBLK + t] : 0;
    int v1 = (256 + t < NBLK) ? cnt[row * NBLK + 256 + t] : 0;
    s[t] = v0; s[256 + t] = v1;
    __syncthreads();
    for (int off = 1; off < 512; off <<= 1) {
        int a = (t >= off) ? s[t - off] : 0;
        int b = (256 + t >= off) ? s[256 + t - off] : 0;
        __syncthreads();
        s[t] += a; s[256 + t] += b;
        __syncthreads();
    }
    if (t < NBLK) cnt[row * NBLK + t] = s[t] - v0;
    if (256 + t < NBLK) cnt[row * NBLK + 256 + t] = s[256 + t] - v1;
    if (t == 0) tot[row] = s[511];
}

__global__ __launch_bounds__(256) void k_scanTot(int* __restrict__ totD,
        int* __restrict__ baseD, int* __restrict__ totS, int* __restrict__ baseS) {
    __shared__ int s[1024];
    int t = threadIdx.x;
    int* tot  = blockIdx.x ? totS  : totD;
    int* base = blockIdx.x ? baseS : baseD;
    int v[4];
    #pragma unroll
    for (int q = 0; q < 4; ++q) {
        int i = q * 256 + t;
        v[q] = (i < NBUK) ? tot[i] : 0;
        s[i] = v[q];
    }
    __syncthreads();
    for (int off = 1; off < 1024; off <<= 1) {
        int a[4];
        #pragma unroll
        for (int q = 0; q < 4; ++q) {
            int i = q * 256 + t;
            a[q] = (i >= off) ? s[i - off] : 0;
        }
        __syncthreads();
        #pragma unroll
        for (int q = 0; q < 4; ++q) s[q * 256 + t] += a[q];
        __syncthreads();
    }
    #pragma unroll
    for (int q = 0; q < 4; ++q) {
        int i = q * 256 + t;
        if (i < NBUK) base[i] = s[i] - v[q];
    }
}

__global__ __launch_bounds__(256) void k_scatter(const int* __restrict__ ei,
        const float* __restrict__ ew, const int* __restrict__ offD,
        const int* __restrict__ offS, const int* __restrict__ baseD,
        const int* __restrict__ baseS, long long* __restrict__ recD,
        long long* __restrict__ recS) {
    __shared__ int curD[NBUK], curS[NBUK];
    int t = threadIdx.x, blk = blockIdx.x;
    for (int b = t; b < NBUK; b += 256) {
        curD[b] = baseD[b] + offD[b * NBLK + blk];
        curS[b] = baseS[b] + offS[b * NBLK + blk];
    }
    __syncthreads();
    int e0 = blk * EPB;
    #pragma unroll
    for (int i = 0; i < 8; ++i) {
        int e = e0 + i * 256 + t;
        if (e < E_EDGES) {
            int sN = ei[e], dN = ei[E_EDGES + e];
            long long wb = (long long)(unsigned)__float_as_uint(ew[e]) << 32;
            int pD = atomicAdd(&curD[dN >> BSH], 1);
            recD[pD] = wb | (unsigned)((sN << BSH) | (dN & (BUKN - 1)));
            int pS = atomicAdd(&curS[sN >> BSH], 1);
            recS[pS] = wb | (unsigned)(sN & (BUKN - 1));
        }
    }
}

__global__ __launch_bounds__(256) void k_deg(const long long* __restrict__ recS,
        const int* __restrict__ totS, const int* __restrict__ baseS,
        float* __restrict__ dinv) {
    __shared__ float degL[BUKN];
    int t = threadIdx.x, b = blockIdx.x;
    if (t < BUKN) degL[t] = 0.f;
    __syncthreads();
    int st = baseS[b], n = totS[b];
    for (int i = t; i < n; i += 256) {
        long long r = recS[st + i];
        atomicAdd(&degL[(int)(r & (BUKN - 1))], __uint_as_float((unsigned)(r >> 32)));
    }
    __syncthreads();
    if (t < BUKN) {
        int node = b * BUKN + t;
        if (node < N_NODES) {
            float dg = degL[t];
            dinv[node] = dg > 0.f ? rsqrtf(dg) : 0.f;
        }
    }
}

// Bucket-grouped records -> exact CSR (cv sorted by dst node), val folded.
__global__ __launch_bounds__(256) void k_csr(const long long* __restrict__ recD,
        const int* __restrict__ totD, const int* __restrict__ baseD,
        const float* __restrict__ dinv, long long* __restrict__ cv,
        int* __restrict__ row_start) {
    __shared__ int cnt[BUKN], cur[BUKN];
    __shared__ float dL[BUKN];
    int t = threadIdx.x, b = blockIdx.x;
    if (t < BUKN) {
        cnt[t] = 0;
        int node = b * BUKN + t;
        dL[t] = (node < N_NODES) ? dinv[node] : 0.f;
    }
    __syncthreads();
    int st = baseD[b], n = totD[b];
    for (int i = t; i < n; i += 256)
        atomicAdd(&cnt[(int)(recD[st + i] & (BUKN - 1))], 1);
    __syncthreads();
    if (t < BUKN) {
        int x = cnt[t];
        int orig = x;
        #pragma unroll
        for (int off = 1; off < BUKN; off <<= 1) {
            int v = __shfl_up(x, off, 64);
            if ((t & 63) >= off) x += v;
        }
        cur[t] = x - orig;
        int node = b * BUKN + t;
        if (node < N_NODES) row_start[node] = st + (x - orig);
    }
    if (b == 0 && t == 0) row_start[N_NODES] = E_EDGES;
    __syncthreads();
    for (int i = t; i < n; i += 256) {
        long long r = recD[st + i];
        int m = (int)(r & 0xffffffffLL);
        float w = __uint_as_float((unsigned)(r >> 32));
        int rr = m & (BUKN - 1);
        int sN = m >> BSH;
        float val = -w * dinv[sN] * dL[rr];
        int pos = st + atomicAdd(&cur[rr], 1);
        cv[pos] = ((long long)__float_as_int(val) << 32) | (unsigned)sN;
    }
}

// SpMM: one wave per row; 16 lanes per edge, 4 edges per gather instruction.
template<int SCALE, int SUB>
__global__ __launch_bounds__(256) void k_spmm(
        const int* __restrict__ row_start, const long long* __restrict__ cv,
        const float* __restrict__ xin, const float* __restrict__ xprev,
        float* __restrict__ out) {
    int wid = (blockIdx.x << 2) + (threadIdx.x >> 6);
    int l = threadIdx.x & 63;
    if (wid >= N_NODES) return;
    int start = row_start[wid];
    int end   = row_start[wid + 1];
    int sub = l >> 4;
    int q   = l & 15;
    float4 acc = make_float4(0.f, 0.f, 0.f, 0.f);
    #pragma unroll 2
    for (int j = start; j < end; j += 8) {
        int jA = j + sub;
        int jB = j + 4 + sub;
        long long pA = (jA < end) ? cv[jA] : 0LL;
        long long pB = (jB < end) ? cv[jB] : 0LL;
        float4 xA = *(const float4*)&xin[(size_t)(unsigned)(pA & 0xffffffffLL) * NC + q * 4];
        float4 xB = *(const float4*)&xin[(size_t)(unsigned)(pB & 0xffffffffLL) * NC + q * 4];
        float vA = __int_as_float((int)(pA >> 32));
        float vB = __int_as_float((int)(pB >> 32));
        acc.x = fmaf(vA, xA.x, acc.x); acc.y = fmaf(vA, xA.y, acc.y);
        acc.z = fmaf(vA, xA.z, acc.z); acc.w = fmaf(vA, xA.w, acc.w);
        acc.x = fmaf(vB, xB.x, acc.x); acc.y = fmaf(vB, xB.y, acc.y);
        acc.z = fmaf(vB, xB.z, acc.z); acc.w = fmaf(vB, xB.w, acc.w);
    }
    #pragma unroll
    for (int m = 16; m <= 32; m <<= 1) {
        acc.x += __shfl_xor(acc.x, m, 64);
        acc.y += __shfl_xor(acc.y, m, 64);
        acc.z += __shfl_xor(acc.z, m, 64);
        acc.w += __shfl_xor(acc.w, m, 64);
    }
    if (sub == 0) {
        float4 r;
        r.x = (float)SCALE * acc.x;
        r.y = (float)SCALE * acc.y;
        r.z = (float)SCALE * acc.z;
        r.w = (float)SCALE * acc.w;
        if (SUB) {
            float4 xo = *(const float4*)&xprev[(size_t)wid * NC + q * 4];
            r.x -= xo.x; r.y -= xo.y; r.z -= xo.z; r.w -= xo.w;
        }
        *(float4*)&out[(size_t)wid * NC + q * 4] = r;
    }
}

// bf16x3 MFMA GRU: 32-node tile (GRUB=1563 blocks, 2x parallelism of R9),
// all 3 matrices staged to LDS in ONE phase (6 independent loads/thread,
// 1 barrier). 4 waves = 4 o-tiles of 16; 72 MFMA/wave.
__global__ __launch_bounds__(256) void k_gru(
        const float* __restrict__ X, const float* __restrict__ Tx1,
        const float* __restrict__ Tx2, const short* __restrict__ WB,
        const float* __restrict__ bxz, const float* __restrict__ bhz,
        const float* __restrict__ bxh, const float* __restrict__ bhh,
        float* __restrict__ out) {
    __shared__ short Ahi[3 * 32 * 64];
    __shared__ short Alo[3 * 32 * 64];
    int tid = threadIdx.x;
    int l = tid & 63;
    int w = tid >> 6;
    int node0 = blockIdx.x * 32;

    const float* ins[3] = {X, Tx1, Tx2};

    // Stage: per matrix 512 float4 units; thread does 2 per matrix, 6 total.
    float4 v[3][2];
    #pragma unroll
    for (int m = 0; m < 3; ++m) {
        const float* ip = ins[m];
        #pragma unroll
        for (int r = 0; r < 2; ++r) {
            int fidx = r * 256 + tid;        // 0..511
            int n = fidx >> 4, c4 = fidx & 15;
            int gn = node0 + n;
            v[m][r] = (gn < N_NODES) ? *(const float4*)&ip[(size_t)gn * 64 + c4 * 4]
                                     : make_float4(0.f, 0.f, 0.f, 0.f);
        }
    }
    #pragma unroll
    for (int m = 0; m < 3; ++m) {
        #pragma unroll
        for (int r = 0; r < 2; ++r) {
            int fidx = r * 256 + tid;
            int n = fidx >> 4, c4 = fidx & 15;
            float4 x = v[m][r];
            unsigned h0 = bf16rne(x.x), h1 = bf16rne(x.y),
                     h2 = bf16rne(x.z), h3 = bf16rne(x.w);
            unsigned q0 = bf16rne(x.x - __uint_as_float(h0 << 16));
            unsigned q1 = bf16rne(x.y - __uint_as_float(h1 << 16));
            unsigned q2 = bf16rne(x.z - __uint_as_float(h2 << 16));
            unsigned q3 = bf16rne(x.w - __uint_as_float(h3 << 16));
            int kk = (c4 * 4) ^ ((n & 7) << 3);    // XOR swizzle
            int base = (m * 32 + n) * 64 + kk;
            *(uint2*)&Ahi[base] = make_uint2(h0 | (h1 << 16), h2 | (h3 << 16));
            *(uint2*)&Alo[base] = make_uint2(q0 | (q1 << 16), q2 | (q3 << 16));
        }
    }
    __syncthreads();

    f32x4 accz[2], acch[2];
    #pragma unroll
    for (int mt = 0; mt < 2; ++mt) {
        accz[mt] = (f32x4){0.f, 0.f, 0.f, 0.f};
        acch[mt] = (f32x4){0.f, 0.f, 0.f, 0.f};
    }
    int o = w * 16 + (l & 15);

    #pragma unroll
    for (int m = 0; m < 3; ++m) {
        const short* wbm = WB + m * 4 * 4096;
        #pragma unroll
        for (int kt = 0; kt < 2; ++kt) {
            int k0 = kt * 32 + (l >> 4) * 8;
            bf16x8 ah[2], al[2];
            #pragma unroll
            for (int mt = 0; mt < 2; ++mt) {
                int row = mt * 16 + (l & 15);
                int kk = k0 ^ ((row & 7) << 3);
                int base = (m * 32 + row) * 64 + kk;
                ah[mt] = *(const bf16x8*)&Ahi[base];
                al[mt] = *(const bf16x8*)&Alo[base];
            }
            bf16x8 bzh = *(const bf16x8*)&wbm[0 * 4096 + o * 64 + k0];
            bf16x8 bzl = *(const bf16x8*)&wbm[1 * 4096 + o * 64 + k0];
            bf16x8 bhh_ = *(const bf16x8*)&wbm[2 * 4096 + o * 64 + k0];
            bf16x8 bhl = *(const bf16x8*)&wbm[3 * 4096 + o * 64 + k0];
            #pragma unroll
            for (int mt = 0; mt < 2; ++mt) {
                accz[mt] = __builtin_amdgcn_mfma_f32_16x16x32_bf16(ah[mt], bzh, accz[mt], 0, 0, 0);
                accz[mt] = __builtin_amdgcn_mfma_f32_16x16x32_bf16(ah[mt], bzl, accz[mt], 0, 0, 0);
                accz[mt] = __builtin_amdgcn_mfma_f32_16x16x32_bf16(al[mt], bzh, accz[mt], 0, 0, 0);
                acch[mt] = __builtin_amdgcn_mfma_f32_16x16x32_bf16(ah[mt], bhh_, acch[mt], 0, 0, 0);
                acch[mt] = __builtin_amdgcn_mfma_f32_16x16x32_bf16(ah[mt], bhl, acch[mt], 0, 0, 0);
                acch[mt] = __builtin_amdgcn_mfma_f32_16x16x32_bf16(al[mt], bhh_, acch[mt], 0, 0, 0);
            }
        }
    }

    // epilogue: C/D layout col=lane&15 (o), row=(lane>>4)*4+r (node)
    float bz = bxz[o] + bhz[o];
    float bh = bxh[o] + bhh[o];
    #pragma unroll
    for (int mt = 0; mt < 2; ++mt) {
        #pragma unroll
        for (int r = 0; r < 4; ++r) {
            int node = node0 + mt * 16 + (l >> 4) * 4 + r;
            if (node < N_NODES) {
                float z = accz[mt][r] + bz;
                float h = acch[mt][r] + bh;
                float sig = 1.f / (1.f + __expf(-z));
                float e2 = __expf(-2.f * h);
                float th = (1.f - e2) / (1.f + e2);
                out[(size_t)node * 64 + o] = (1.f - sig) * th;
            }
        }
    }
}

extern "C" void kernel_launch(void* const* d_in, const int* in_sizes, int n_in,
                              void* d_out, int out_size, void* d_ws, size_t ws_size,
                              hipStream_t stream) {
    const float* X   = (const float*)d_in[0];
    const int*   ei  = (const int*)d_in[1];
    const float* ew  = (const float*)d_in[2];
    const float* Wxz = (const float*)d_in[3];
    const float* Wxh = (const float*)d_in[7];
    const float* bxz = (const float*)d_in[9];
    const float* bhz = (const float*)d_in[10];
    const float* bxh = (const float*)d_in[13];
    const float* bhh = (const float*)d_in[14];
    float* out = (float*)d_out;

    float* ws_f = (float*)d_ws;
    int*   ws_i = (int*)d_ws;

    long long* cv       = (long long*)(ws_i + OFF_CV);
    int*       rowstart = ws_i + OFF_ROWSTART;
    int*       totD     = ws_i + OFF_TOTD;
    int*       baseD    = ws_i + OFF_BASED;
    int*       totS     = ws_i + OFF_TOTS;
    int*       baseS    = ws_i + OFF_BASES;
    float*     tx1      = ws_f + OFF_TX1;
    long long* recD     = (long long*)(ws_i + OFF_RECD);
    float*     dinv     = ws_f + OFF_DINV;
    int*       cntD     = ws_i + OFF_CNTD;
    float*     tx2      = ws_f + OFF_TX2;
    long long* recS     = (long long*)(ws_i + OFF_RECS);
    int*       cntS     = ws_i + OFF_CNTS;
    short*     WB       = (short*)(ws_i + OFF_WB);

    const int TB = 256;
    k_hist<<<NBLK + 6, TB, 0, stream>>>(ei, cntD, cntS, Wxz, Wxh, WB);
    k_scanPB<<<2 * NBUK, TB, 0, stream>>>(cntD, cntS, totD, totS);
    k_scanTot<<<2, TB, 0, stream>>>(totD, baseD, totS, baseS);
    k_scatter<<<NBLK, TB, 0, stream>>>(ei, ew, cntD, cntS, baseD, baseS, recD, recS);
    k_deg<<<NBUK, TB, 0, stream>>>(recS, totS, baseS, dinv);
    k_csr<<<NBUK, TB, 0, stream>>>(recD, totD, baseD, dinv, cv, rowstart);

    // Tx1 = L_hat @ X
    k_spmm<1, 0><<<(N_NODES + 3) / 4, TB, 0, stream>>>(rowstart, cv, X, X, tx1);
    // Tx2 = 2 * L_hat @ Tx1 - X
    k_spmm<2, 1><<<(N_NODES + 3) / 4, TB, 0, stream>>>(rowstart, cv, tx1, X, tx2);

    k_gru<<<GRUB, TB, 0, stream>>>(X, tx1, tx2, WB, bxz, bhz, bxh, bhh, out);
}